// Round 13
// baseline (2387.644 us; speedup 1.0000x reference)
//
#include <hip/hip_runtime.h>
#include <math.h>

#define TS 64
#define IFACE_N 471
#define EPS_ 1e-6f

// iface column offsets
#define OFF_RK 0
#define OFF_RB 256
#define OFF_WK 260
#define OFF_WB 324
#define OFF_EV 325
#define OFF_WV 389
#define OFF_FG 453
#define OFF_AG 457
#define OFF_WG 458
#define OFF_RM 459

// ws float offsets
#define O_HX   0         // 524288 : hx[t*16+b][512]; overwritten in-place with h(t)
#define O_RS   524288    // 262144 : rv(t) save (t*16+b)x256
#define O_L    1048576   // 1048576 (L zeroed in kLoop prologue; M lives in LDS)
// packed bf16 weights, transposed [col][kpair], padded strides:
#define WIPS 260
#define WHPS 132
#define O_WIP  2097152   // 471*260 = 122460 uints   W_iface (256 kp)
#define O_WHP  2219612   // 512*132 = 67584          W_hid[512:768] (128 kp)

__device__ __forceinline__ float sigmoidf_(float x){ return 1.f/(1.f+expf(-x)); }
__device__ __forceinline__ float oneplusf_(float x){ return 1.f+fmaxf(x,0.f)+log1pf(expf(-fabsf(x))); }
__device__ __forceinline__ float wsum_(float v){
#pragma unroll
  for(int off=32; off>0; off>>=1) v += __shfl_xor(v,off,64);
  return v;
}
__device__ __forceinline__ float wmax_(float v){
#pragma unroll
  for(int off=32; off>0; off>>=1) v = fmaxf(v,__shfl_xor(v,off,64));
  return v;
}
__device__ __forceinline__ unsigned bf16rne_(float f){
  unsigned u = __float_as_uint(f);
  return (u + 0x7FFFu + ((u >> 16) & 1u)) >> 16;
}
__device__ __forceinline__ unsigned bf16pack_(float lo, float hi){
  return bf16rne_(lo) | (bf16rne_(hi) << 16);
}
__device__ __forceinline__ float bflo_(unsigned p){ return __uint_as_float(p << 16); }
__device__ __forceinline__ float bfhi_(unsigned p){ return __uint_as_float(p & 0xFFFF0000u); }

// readlane: fetch wave-uniform value from a lane's VGPR (VALU pipe, not DS)
__device__ __forceinline__ float rlf_(float v, int l){
  return __uint_as_float(__builtin_amdgcn_readlane(__float_as_uint(v), l));
}

// dot8 against 8 consecutive h values held distributed in vh (4/lane), lanes lb,lb+1
__device__ __forceinline__ float dot8rl_(uint4 p, float4 vh, int lb, float acc){
  acc = fmaf(rlf_(vh.x,lb),   bflo_(p.x), acc);
  acc = fmaf(rlf_(vh.y,lb),   bfhi_(p.x), acc);
  acc = fmaf(rlf_(vh.z,lb),   bflo_(p.y), acc);
  acc = fmaf(rlf_(vh.w,lb),   bfhi_(p.y), acc);
  acc = fmaf(rlf_(vh.x,lb+1), bflo_(p.z), acc);
  acc = fmaf(rlf_(vh.y,lb+1), bfhi_(p.z), acc);
  acc = fmaf(rlf_(vh.z,lb+1), bflo_(p.w), acc);
  acc = fmaf(rlf_(vh.w,lb+1), bfhi_(p.w), acc);
  return acc;
}

// dot8 against 8 consecutive rv values held distributed in vr (2/lane), lanes lb..lb+3
__device__ __forceinline__ float dot8rl2_(uint4 p, float2 vr, int lb, float acc){
  acc = fmaf(rlf_(vr.x,lb),   bflo_(p.x), acc);
  acc = fmaf(rlf_(vr.y,lb),   bfhi_(p.x), acc);
  acc = fmaf(rlf_(vr.x,lb+1), bflo_(p.y), acc);
  acc = fmaf(rlf_(vr.y,lb+1), bfhi_(p.y), acc);
  acc = fmaf(rlf_(vr.x,lb+2), bflo_(p.z), acc);
  acc = fmaf(rlf_(vr.y,lb+2), bfhi_(p.z), acc);
  acc = fmaf(rlf_(vr.x,lb+3), bflo_(p.w), acc);
  acc = fmaf(rlf_(vr.y,lb+3), bfhi_(p.w), acc);
  return acc;
}

// ===================== kPrep: weight pack (kConv) + input GEMM (kPre), merged ======
__global__ void __launch_bounds__(256)
kPrep(const float* __restrict__ W_hid, const float* __restrict__ W_iface,
      const float* __restrict__ x, const float* __restrict__ b_hid,
      float* __restrict__ ws)
{
  // --- pack + transpose recurrent-path weights (bf16) ---
  unsigned* Wip = (unsigned*)(ws + O_WIP);
  unsigned* Whp = (unsigned*)(ws + O_WHP);
  int g = blockIdx.x*256 + threadIdx.x;          // 65536 threads
  for (int i = g; i < 471*256; i += 65536) {
    int c = i >> 8, kp = i & 255;
    Wip[c*WIPS + kp] = bf16pack_(W_iface[(size_t)(2*kp)*IFACE_N + c],
                                 W_iface[(size_t)(2*kp+1)*IFACE_N + c]);
  }
  {
    int c = g >> 7, kp = g & 127;
    Whp[c*WHPS + kp] = bf16pack_(W_hid[(size_t)(512 + 2*kp)*512 + c],
                                 W_hid[(size_t)(513 + 2*kp)*512 + c]);
  }

  // --- hx = x @ W_hid[0:512] + b (kPre body; independent of the packing above) ---
  const int tid = threadIdx.x, blk = blockIdx.x;
  const int r0 = (blk >> 1) * 8, col = (blk & 1) * 256 + tid;
  __shared__ float xs[8][512];
  for (int i = tid; i < 8*512; i += 256) {
    int rr = i >> 9, k = i & 511;
    xs[rr][k] = x[(size_t)(r0+rr)*512 + k];
  }
  __syncthreads();
  float a0=0,a1=0,a2=0,a3=0,a4=0,a5=0,a6=0,a7=0;
  const float* Wp = W_hid + col;
#pragma unroll 4
  for (int k = 0; k < 512; k++) {
    float w = Wp[(size_t)k*512];
    a0 = fmaf(xs[0][k], w, a0); a1 = fmaf(xs[1][k], w, a1);
    a2 = fmaf(xs[2][k], w, a2); a3 = fmaf(xs[3][k], w, a3);
    a4 = fmaf(xs[4][k], w, a4); a5 = fmaf(xs[5][k], w, a5);
    a6 = fmaf(xs[6][k], w, a6); a7 = fmaf(xs[7][k], w, a7);
  }
  float bh = b_hid[col];
  float av[8] = {a0,a1,a2,a3,a4,a5,a6,a7};
#pragma unroll
  for (int i = 0; i < 8; i++)
    ws[O_HX + (size_t)(r0+i)*512 + col] = av[i] + bh;
}

// iface value x (<471) read directly from k-split psum (no combine phase)
#define IFC(x) (psum[(x)] + psum[512+(x)])

// ===================== kLoop: 16 independent per-batch blocks, all 64 steps =======
__global__ void __launch_bounds__(1024, 4)
kLoop(const unsigned* __restrict__ WipT, const unsigned* __restrict__ WhpT,
      float* __restrict__ hx, float* __restrict__ rvs, float* __restrict__ Lall)
{
  const int tid = threadIdx.x, b = blockIdx.x;
  const int wv = tid >> 6, lane = tid & 63;

  __shared__ float hl[512];
  __shared__ float psum[1024];
  __shared__ float psumB[1024];
  __shared__ alignas(16) float ul[256];
  __shared__ alignas(16) float pOl[256];
  __shared__ float pNl[256];
  __shared__ alignas(16) float wwl[256];
  __shared__ alignas(16) float rwl[1024];
  __shared__ float wkn[64], rknl[256];
  __shared__ alignas(16) float evl[64], wvl[64];
  __shared__ float ssorted[256];
  __shared__ int   sidx[256];
  __shared__ float sal[256], siml[256], cwl[256];
  __shared__ float fwdl[1024], bwdl[1024], rcs[1024];
  __shared__ alignas(16) float bb[16][2][260];
  __shared__ float sSa;
  __shared__ alignas(16) float Ml[16384];    // M lives in LDS (block-private)

  float* Lg = Lall + (size_t)b*65536;

  // prologue: zero this block's L slice (replaces kInit), init state
  {
    float4 z4 = {0.f, 0.f, 0.f, 0.f};
    float4* Lz = (float4*)Lg;
    for (int i = tid; i < 16384; i += 1024) Lz[i] = z4;
  }
  if (tid < 512) hl[tid] = fmaxf(hx[(size_t)b*512 + tid], 0.f);   // h(0)
  rwl[tid] = 0.f;
  if (tid < 256){ ul[tid]=0.f; pOl[tid]=0.f; wwl[tid]=0.f; }
  for (int i = tid; i < 16384; i += 1024) Ml[i] = 1e-6f;
  __syncthreads();

  for (int t = 0; t < TS; t++) {
    // ---- P1: iface = h @ W_iface (bf16, distributed-h + readlane) ----
    {
      int col = tid & 511, kseg = tid >> 9;
      // one ds_read_b128 per lane distributes this wave's 256 h values
      float4 vh = *(const float4*)(hl + kseg*256 + (lane << 2));
      float a0 = 0.f, a1 = 0.f;
      if (col < IFACE_N) {
        const uint4* Wp = (const uint4*)(WipT + col*WIPS + kseg*128);
#pragma unroll
        for (int q4 = 0; q4 < 32; q4 += 2) {
          a0 = dot8rl_(Wp[q4],   vh, 2*q4,     a0);
          a1 = dot8rl_(Wp[q4+1], vh, 2*q4 + 2, a1);
        }
      }
      psum[tid] = a0 + a1;
    }
    __syncthreads();

    // ---- P2: usage update + key norms + gate vectors (read psum pairs) ----
    if (tid < 256) {
      float ret = 1.f;
#pragma unroll
      for (int r = 0; r < 4; r++) {
        float fg = sigmoidf_(IFC(OFF_FG + r));
        ret *= (1.f - fg * rwl[r*256 + tid]);
      }
      float uo = ul[tid], wo = wwl[tid];
      ul[tid] = (uo + wo - uo*wo) * ret;
    } else if (tid >= 448 && tid < 512) {              // wave 7: wk norm
      float kv = IFC(OFF_WK + lane);
      float ss = wsum_(kv*kv);
      wkn[lane] = kv / (sqrtf(ss) + EPS_);
    } else if (tid >= 512 && tid < 768) {              // waves 8..11: rk norms
      int r = wv - 8;
      float kv = IFC(OFF_RK + r*64 + lane);
      float ss = wsum_(kv*kv);
      rknl[r*64 + lane] = kv / (sqrtf(ss) + EPS_);
    } else if (tid >= 768 && tid < 832) {              // wave 12: erase vec
      evl[lane] = sigmoidf_(IFC(OFF_EV + lane));
    } else if (tid >= 832 && tid < 896) {              // wave 13: write vec
      wvl[lane] = IFC(OFF_WV + lane);
    }
    __syncthreads();

    // ---- P3: MERGED stable rank argsort + content-dot over OLD M ----
    {
      int n = tid >> 2, q = tid & 3;
      const float4* Mp = (const float4*)(Ml + n*64 + q*16);
      float4 m0 = Mp[0], m1 = Mp[1], m2 = Mp[2], m3 = Mp[3];
      float un = ul[n];
      const float4* sp4 = (const float4*)(ul + q*64);
      int cnt = 0;
#pragma unroll 4
      for (int m4 = 0; m4 < 16; m4++) {
        float4 um = sp4[m4];
        int gm = q*64 + m4*4;
        cnt += (um.x < un || (um.x == un && gm   < n)) ? 1 : 0;
        cnt += (um.y < un || (um.y == un && gm+1 < n)) ? 1 : 0;
        cnt += (um.z < un || (um.z == un && gm+2 < n)) ? 1 : 0;
        cnt += (um.w < un || (um.w == un && gm+3 < n)) ? 1 : 0;
      }
      cnt += __shfl_xor(cnt, 1, 64);
      cnt += __shfl_xor(cnt, 2, 64);
      const float* kp = wkn + q*16;
      float ss = m0.x*m0.x + m0.y*m0.y + m0.z*m0.z + m0.w*m0.w
               + m1.x*m1.x + m1.y*m1.y + m1.z*m1.z + m1.w*m1.w
               + m2.x*m2.x + m2.y*m2.y + m2.z*m2.z + m2.w*m2.w
               + m3.x*m3.x + m3.y*m3.y + m3.z*m3.z + m3.w*m3.w;
      float dt = m0.x*kp[0] + m0.y*kp[1] + m0.z*kp[2] + m0.w*kp[3]
               + m1.x*kp[4] + m1.y*kp[5] + m1.z*kp[6] + m1.w*kp[7]
               + m2.x*kp[8] + m2.y*kp[9] + m2.z*kp[10] + m2.w*kp[11]
               + m3.x*kp[12] + m3.y*kp[13] + m3.z*kp[14] + m3.w*kp[15];
      ss += __shfl_xor(ss,1,64); ss += __shfl_xor(ss,2,64);
      dt += __shfl_xor(dt,1,64); dt += __shfl_xor(dt,2,64);
      if (q == 0) {
        ssorted[cnt] = un; sidx[cnt] = n;
        float wb = oneplusf_(IFC(OFF_WB));
        siml[n] = wb * dt / (sqrtf(ss) + EPS_);
      }
    }
    __syncthreads();

    // ---- P4: cumprod alloc + Sa (wave 0) | write softmax (waves 4..7) ----
    if (wv == 0) {
      float carry = 1.f;
      float s_acc = 0.f;
#pragma unroll
      for (int c2 = 0; c2 < 4; c2++) {
        float v0 = ssorted[c2*64 + lane];
        float v = v0;
#pragma unroll
        for (int off = 1; off < 64; off <<= 1) {
          float uu = __shfl_up(v, off, 64);
          if (lane >= off) v *= uu;
        }
        float e = __shfl_up(v, 1, 64);
        if (lane == 0) e = 1.f;
        float av = (1.f - v0) * e * carry;
        sal[sidx[c2*64 + lane]] = av;
        s_acc += av;
        carry *= __shfl(v, 63, 64);
      }
      float S = wsum_(s_acc);
      if (lane == 0) sSa = S;
    } else if (wv >= 4 && wv < 8) {
      int s = tid - 256;                   // 0..255
      float v0 = siml[lane], v1 = siml[64+lane], v2 = siml[128+lane], v3 = siml[192+lane];
      float mx = wmax_(fmaxf(fmaxf(v0,v1), fmaxf(v2,v3)));
      float ssum = wsum_(expf(v0-mx)+expf(v1-mx)+expf(v2-mx)+expf(v3-mx));
      cwl[s] = expf(siml[s]-mx) / ssum;
    }
    __syncthreads();

    // ---- P5: ww + pN (wws analytic: sum(cw)=1, sum(a)=Sa) ----
    if (tid < 256) {
      float ag = sigmoidf_(IFC(OFF_AG));
      float wg = sigmoidf_(IFC(OFF_WG));
      float wwn = wg * (ag*sal[tid] + (1.f-ag)*cwl[tid]);
      wwl[tid] = wwn;
      float wws = wg * (ag*sSa + (1.f-ag));
      pNl[tid] = (1.f - wws)*pOl[tid] + wwn;
    }
    __syncthreads();

    // ---- P7: L update + fwd (4-value butterfly per row) + bwd (2-round bb
    //          staging, with P8 (M update + rc logits) overlapped on waves 8..15) ----
    {
      const int j0 = lane*4;
      const float4 wj  = *(const float4*)(wwl + j0);
      const float4 pj  = *(const float4*)(pOl + j0);
      const float4 rw0 = *(const float4*)(rwl + j0);
      const float4 rw1 = *(const float4*)(rwl + 256 + j0);
      const float4 rw2 = *(const float4*)(rwl + 512 + j0);
      const float4 rw3 = *(const float4*)(rwl + 768 + j0);
      // distributed wave-uniform values: lane l holds rw[head l>>4][row l&15],
      // and ww[row l&15]; accessed via readlane (VALU) instead of DS broadcasts.
      float vrw = rwl[(lane >> 4)*256 + wv*16 + (lane & 15)];
      float vww = wwl[wv*16 + (lane & 15)];
      float4 ba0 = {0,0,0,0}, ba1 = {0,0,0,0}, ba2 = {0,0,0,0}, ba3 = {0,0,0,0};
      float4* Lrow = (float4*)Lg;
#pragma unroll 4
      for (int ii = 0; ii < 16; ii++) {
        int i = wv*16 + ii;
        float wwi = rlf_(vww, ii);
        float4 lv = Lrow[i*64 + lane];
        float s = 1.f - wwi;
        float4 nv;
        nv.x = (s - wj.x)*lv.x + wwi*pj.x;
        nv.y = (s - wj.y)*lv.y + wwi*pj.y;
        nv.z = (s - wj.z)*lv.z + wwi*pj.z;
        nv.w = (s - wj.w)*lv.w + wwi*pj.w;
        if (j0   == i) nv.x = 0.f;
        if (j0+1 == i) nv.y = 0.f;
        if (j0+2 == i) nv.z = 0.f;
        if (j0+3 == i) nv.w = 0.f;
        Lrow[i*64 + lane] = nv;
        float f0 = nv.x*rw0.x + nv.y*rw0.y + nv.z*rw0.z + nv.w*rw0.w;
        float f1 = nv.x*rw1.x + nv.y*rw1.y + nv.z*rw1.z + nv.w*rw1.w;
        float f2 = nv.x*rw2.x + nv.y*rw2.y + nv.z*rw2.z + nv.w*rw2.w;
        float f3 = nv.x*rw3.x + nv.y*rw3.y + nv.z*rw3.z + nv.w*rw3.w;
        // 4-value wave reduction: transpose onto lane&3, then 4 xor levels.
        float u0 = (lane & 1) ? f1 : f0;
        float v0 = (lane & 1) ? f0 : f1;
        u0 += __shfl_xor(v0, 1, 64);
        float u1 = (lane & 1) ? f3 : f2;
        float v1 = (lane & 1) ? f2 : f3;
        u1 += __shfl_xor(v1, 1, 64);
        float u2 = (lane & 2) ? u1 : u0;
        float v2 = (lane & 2) ? u0 : u1;
        u2 += __shfl_xor(v2, 2, 64);
        u2 += __shfl_xor(u2, 4, 64);
        u2 += __shfl_xor(u2, 8, 64);
        u2 += __shfl_xor(u2, 16, 64);
        u2 += __shfl_xor(u2, 32, 64);
        if (lane < 4) fwdl[lane*256 + i] = u2;     // lane k holds sum of f_k
        float ri0 = rlf_(vrw, ii);
        float ri1 = rlf_(vrw, 16 + ii);
        float ri2 = rlf_(vrw, 32 + ii);
        float ri3 = rlf_(vrw, 48 + ii);
        ba0.x = fmaf(ri0, nv.x, ba0.x); ba0.y = fmaf(ri0, nv.y, ba0.y);
        ba0.z = fmaf(ri0, nv.z, ba0.z); ba0.w = fmaf(ri0, nv.w, ba0.w);
        ba1.x = fmaf(ri1, nv.x, ba1.x); ba1.y = fmaf(ri1, nv.y, ba1.y);
        ba1.z = fmaf(ri1, nv.z, ba1.z); ba1.w = fmaf(ri1, nv.w, ba1.w);
        ba2.x = fmaf(ri2, nv.x, ba2.x); ba2.y = fmaf(ri2, nv.y, ba2.y);
        ba2.z = fmaf(ri2, nv.z, ba2.z); ba2.w = fmaf(ri2, nv.w, ba2.w);
        ba3.x = fmaf(ri3, nv.x, ba3.x); ba3.y = fmaf(ri3, nv.y, ba3.y);
        ba3.z = fmaf(ri3, nv.z, ba3.z); ba3.w = fmaf(ri3, nv.w, ba3.w);
      }

      // save h(t) here: its store drains with the L stores at the next barrier
      if (tid < 512) hx[(size_t)(t*16 + b)*512 + tid] = hl[tid];

      // bwd staging: 2 rounds, 2 heads per round; P8 halves run on waves 8..15
#pragma unroll
      for (int rr = 0; rr < 2; rr++) {
        float4 vA = (rr == 0) ? ba0 : ba2;
        float4 vB = (rr == 0) ? ba1 : ba3;
        *(float4*)&bb[wv][0][j0] = vA;
        *(float4*)&bb[wv][1][j0] = vB;
        __syncthreads();
        if (tid < 512) {
          int r2 = tid >> 8, col = tid & 255;
          float s = 0.f;
#pragma unroll
          for (int w2 = 0; w2 < 16; w2++) s += bb[w2][r2][col];
          bwdl[(rr*2 + r2)*256 + col] = s;
          if (rr == 1 && tid < 256) pOl[tid] = pNl[tid];
        } else {
          // P8 half: M update + rc logits for n in [rr*128, rr*128+128)
          int s2 = tid - 512;                 // 0..511
          int n = rr*128 + (s2 >> 2), q = s2 & 3;
          float wwn = wwl[n];
          float4* Mp = (float4*)(Ml + n*64 + q*16);
          float ss = 0.f, d0 = 0.f, d1 = 0.f, d2 = 0.f, d3 = 0.f;
#pragma unroll
          for (int i = 0; i < 4; i++) {
            float4 mv = Mp[i];
            int w0 = q*16 + i*4;
            float4 ev = *(const float4*)(evl + w0);
            float4 wq = *(const float4*)(wvl + w0);
            float4 nv;
            nv.x = mv.x*(1.f - wwn*ev.x) + wwn*wq.x;
            nv.y = mv.y*(1.f - wwn*ev.y) + wwn*wq.y;
            nv.z = mv.z*(1.f - wwn*ev.z) + wwn*wq.z;
            nv.w = mv.w*(1.f - wwn*ev.w) + wwn*wq.w;
            Mp[i] = nv;
            ss += nv.x*nv.x + nv.y*nv.y + nv.z*nv.z + nv.w*nv.w;
            const float* k0 = rknl + w0;
            const float* k1 = rknl + 64 + w0;
            const float* k2 = rknl + 128 + w0;
            const float* k3 = rknl + 192 + w0;
            d0 += nv.x*k0[0] + nv.y*k0[1] + nv.z*k0[2] + nv.w*k0[3];
            d1 += nv.x*k1[0] + nv.y*k1[1] + nv.z*k1[2] + nv.w*k1[3];
            d2 += nv.x*k2[0] + nv.y*k2[1] + nv.z*k2[2] + nv.w*k2[3];
            d3 += nv.x*k3[0] + nv.y*k3[1] + nv.z*k3[2] + nv.w*k3[3];
          }
          // transpose d0..d3 onto lane&3 within the quad, full ss reduce
          float a  = (lane & 1) ? d1 : d0;
          float bq = (lane & 1) ? d0 : d1;
          a += __shfl_xor(bq, 1, 64);
          float c2 = (lane & 1) ? d3 : d2;
          float dq = (lane & 1) ? d2 : d3;
          c2 += __shfl_xor(dq, 1, 64);
          float e  = (lane & 2) ? c2 : a;
          float fq = (lane & 2) ? a : c2;
          e += __shfl_xor(fq, 2, 64);
          ss += __shfl_xor(ss,1,64); ss += __shfl_xor(ss,2,64);
          float inv = 1.f/(sqrtf(ss) + EPS_);
          rcs[q*256 + n] = oneplusf_(IFC(OFF_RB + q)) * e * inv;
        }
        __syncthreads();
      }
    }

    // ---- P9: rc softmax ----
    if (wv < 4) {
      float* rp = rcs + wv*256;
      float v0 = rp[lane], v1 = rp[64+lane], v2 = rp[128+lane], v3 = rp[192+lane];
      float mx = wmax_(fmaxf(fmaxf(v0,v1), fmaxf(v2,v3)));
      float e0 = expf(v0-mx), e1 = expf(v1-mx), e2 = expf(v2-mx), e3 = expf(v3-mx);
      float inv = 1.f / wsum_(e0+e1+e2+e3);
      rp[lane] = e0*inv; rp[64+lane] = e1*inv; rp[128+lane] = e2*inv; rp[192+lane] = e3*inv;
    }
    __syncthreads();

    // ---- P10: rw_new (rm weights from psum pairs) ----
    {
      int r = tid >> 8;
      float e0 = IFC(OFF_RM + r*3+0), e1 = IFC(OFF_RM + r*3+1), e2 = IFC(OFF_RM + r*3+2);
      float mx = fmaxf(e0, fmaxf(e1, e2));
      float x0 = expf(e0-mx), x1 = expf(e1-mx), x2 = expf(e2-mx);
      float inv = 1.f/(x0+x1+x2);
      rwl[tid] = (x0*bwdl[tid] + x1*rcs[tid] + x2*fwdl[tid]) * inv;
    }
    __syncthreads();

    // ---- P11: rv partials (M from LDS; rw distributed + readlane) ----
    {
      int w = tid & 63, r = (tid >> 6) & 3, c = tid >> 8;
      float vrp = rwl[r*256 + c*64 + lane];   // 1 ds_read; values uniform per wave
      const float* Mp = Ml + c*4096 + w;
      float a0 = 0.f, a1 = 0.f;
#pragma unroll
      for (int n = 0; n < 64; n += 2) {
        a0 = fmaf(Mp[(n  )*64], rlf_(vrp, n  ), a0);
        a1 = fmaf(Mp[(n+1)*64], rlf_(vrp, n+1), a1);
      }
      psum[c*256 + r*64 + w] = a0 + a1;
    }
    __syncthreads();

    // ---- P12: gather rv from psum partials (no combine phase/barrier); save rvs;
    //           h(t+1) GEMV into psumB (separate buffer -> no psum read/write race) ----
    {
      int kseg = tid >> 9;
      int base = kseg*128 + (lane << 1);
      float2 q0 = *(const float2*)(psum +       base);
      float2 q1 = *(const float2*)(psum + 256 + base);
      float2 q2 = *(const float2*)(psum + 512 + base);
      float2 q3 = *(const float2*)(psum + 768 + base);
      float2 vr;
      vr.x = (q0.x + q1.x) + (q2.x + q3.x);
      vr.y = (q0.y + q1.y) + (q2.y + q3.y);
      // waves 0 and 8 jointly cover positions 0..255 exactly once
      if (wv == 0 || wv == 8)
        *(float2*)(rvs + (size_t)(t*16 + b)*256 + base) = vr;
      if (t + 1 < TS) {
        int col = tid & 511;
        const uint4* Wp = (const uint4*)(WhpT + col*WHPS + kseg*64);
        float a0 = 0.f, a1 = 0.f;
#pragma unroll
        for (int q4 = 0; q4 < 16; q4 += 2) {
          a0 = dot8rl2_(Wp[q4],   vr, 4*q4,     a0);
          a1 = dot8rl2_(Wp[q4+1], vr, 4*q4 + 4, a1);
        }
        psumB[tid] = a0 + a1;
      }
    }
    if (t + 1 < TS) {
      __syncthreads();
      if (tid < 512)
        hl[tid] = fmaxf(hx[(size_t)((t+1)*16 + b)*512 + tid] + psumB[tid] + psumB[512+tid], 0.f);
      __syncthreads();
    }
  }
}

// ===================== kOut: out(t) = h(t)@W_out + rv(t)@W_memout (all t) =========
__global__ void __launch_bounds__(1024)
kOut(const float* __restrict__ W_out, const float* __restrict__ W_memout,
     const float* __restrict__ hsv, const float* __restrict__ rvs,
     float* __restrict__ out)
{
  const int tid = threadIdx.x, blk = blockIdx.x;
  const int rg = blk >> 2, cq = blk & 3;
  __shared__ float hs[16*512];
  __shared__ float rs[16*256];
  for (int i = tid; i < 16*512; i += 1024) hs[i] = hsv[(size_t)rg*16*512 + i];
  for (int i = tid; i < 16*256; i += 1024) rs[i] = rvs[(size_t)rg*16*256 + i];
  __syncthreads();
  int c  = cq*128 + (tid & 127);
  int ro = tid >> 7;                    // 0..7 -> rows 2*ro, 2*ro+1
  const float* h0 = hs + (2*ro)*512;
  const float* h1 = h0 + 512;
  const float* r0 = rs + (2*ro)*256;
  const float* r1 = r0 + 256;
  float a0 = 0.f, a1 = 0.f;
  const float* Wp = W_out + c;
#pragma unroll 8
  for (int k = 0; k < 512; k++) {
    float w = Wp[(size_t)k*512];
    a0 = fmaf(h0[k], w, a0);
    a1 = fmaf(h1[k], w, a1);
  }
  const float* Wm = W_memout + c;
#pragma unroll 8
  for (int k = 0; k < 256; k++) {
    float w = Wm[(size_t)k*512];
    a0 = fmaf(r0[k], w, a0);
    a1 = fmaf(r1[k], w, a1);
  }
  out[(size_t)(rg*16 + 2*ro)*512 + c]     = a0;
  out[(size_t)(rg*16 + 2*ro + 1)*512 + c] = a1;
}

extern "C" void kernel_launch(void* const* d_in, const int* in_sizes, int n_in,
                              void* d_out, int out_size, void* d_ws, size_t ws_size,
                              hipStream_t stream) {
  (void)in_sizes; (void)n_in; (void)out_size; (void)ws_size;
  const float* x        = (const float*)d_in[0];
  const float* W_hid    = (const float*)d_in[1];
  const float* b_hid    = (const float*)d_in[2];
  const float* W_iface  = (const float*)d_in[3];
  const float* W_out    = (const float*)d_in[4];
  const float* W_memout = (const float*)d_in[5];
  float* outp = (float*)d_out;
  float* ws   = (float*)d_ws;

  hipLaunchKernelGGL(kPrep, dim3(256), dim3(256), 0, stream,
                     W_hid, W_iface, x, b_hid, ws);

  const unsigned* WipT = (const unsigned*)(ws + O_WIP);
  const unsigned* WhpT = (const unsigned*)(ws + O_WHP);
  float* hx   = ws + O_HX;
  float* rvs  = ws + O_RS;
  float* Lall = ws + O_L;

  hipLaunchKernelGGL(kLoop, dim3(16), dim3(1024), 0, stream,
                     WipT, WhpT, hx, rvs, Lall);
  hipLaunchKernelGGL(kOut, dim3(256), dim3(1024), 0, stream,
                     W_out, W_memout, hx, rvs, outp);
}

// Round 14
// 2370.185 us; speedup vs baseline: 1.0074x; 1.0074x over previous
//
#include <hip/hip_runtime.h>
#include <math.h>

#define TS 64
#define IFACE_N 471
#define EPS_ 1e-6f

// iface column offsets
#define OFF_RK 0
#define OFF_RB 256
#define OFF_WK 260
#define OFF_WB 324
#define OFF_EV 325
#define OFF_WV 389
#define OFF_FG 453
#define OFF_AG 457
#define OFF_WG 458
#define OFF_RM 459

// ws float offsets
#define O_HX   0         // 524288 : hx[t*16+b][512]; overwritten in-place with h(t)
#define O_RS   524288    // 262144 : rv(t) save (t*16+b)x256
#define O_L    1048576   // 1048576 (L zeroed in kLoop prologue; M lives in LDS)
// packed bf16 weights, transposed [col][kpair], padded strides:
#define WIPS 260
#define WHPS 132
#define O_WIP  2097152   // 471*260 = 122460 uints   W_iface (256 kp)
#define O_WHP  2219612   // 512*132 = 67584          W_hid[512:768] (128 kp)

__device__ __forceinline__ float sigmoidf_(float x){ return 1.f/(1.f+expf(-x)); }
__device__ __forceinline__ float oneplusf_(float x){ return 1.f+fmaxf(x,0.f)+log1pf(expf(-fabsf(x))); }
__device__ __forceinline__ float wsum_(float v){
#pragma unroll
  for(int off=32; off>0; off>>=1) v += __shfl_xor(v,off,64);
  return v;
}
__device__ __forceinline__ float wmax_(float v){
#pragma unroll
  for(int off=32; off>0; off>>=1) v = fmaxf(v,__shfl_xor(v,off,64));
  return v;
}
__device__ __forceinline__ unsigned bf16rne_(float f){
  unsigned u = __float_as_uint(f);
  return (u + 0x7FFFu + ((u >> 16) & 1u)) >> 16;
}
__device__ __forceinline__ unsigned bf16pack_(float lo, float hi){
  return bf16rne_(lo) | (bf16rne_(hi) << 16);
}
__device__ __forceinline__ float bflo_(unsigned p){ return __uint_as_float(p << 16); }
__device__ __forceinline__ float bfhi_(unsigned p){ return __uint_as_float(p & 0xFFFF0000u); }

// readlane: fetch wave-uniform value from a lane's VGPR (VALU pipe, not DS)
__device__ __forceinline__ float rlf_(float v, int l){
  return __uint_as_float(__builtin_amdgcn_readlane(__float_as_uint(v), l));
}

// dot8 against 8 consecutive h values held distributed in vh (4/lane), lanes lb,lb+1
__device__ __forceinline__ float dot8rl_(uint4 p, float4 vh, int lb, float acc){
  acc = fmaf(rlf_(vh.x,lb),   bflo_(p.x), acc);
  acc = fmaf(rlf_(vh.y,lb),   bfhi_(p.x), acc);
  acc = fmaf(rlf_(vh.z,lb),   bflo_(p.y), acc);
  acc = fmaf(rlf_(vh.w,lb),   bfhi_(p.y), acc);
  acc = fmaf(rlf_(vh.x,lb+1), bflo_(p.z), acc);
  acc = fmaf(rlf_(vh.y,lb+1), bfhi_(p.z), acc);
  acc = fmaf(rlf_(vh.z,lb+1), bflo_(p.w), acc);
  acc = fmaf(rlf_(vh.w,lb+1), bfhi_(p.w), acc);
  return acc;
}

// dot8 against 8 consecutive rv values held distributed in vr (2/lane), lanes lb..lb+3
__device__ __forceinline__ float dot8rl2_(uint4 p, float2 vr, int lb, float acc){
  acc = fmaf(rlf_(vr.x,lb),   bflo_(p.x), acc);
  acc = fmaf(rlf_(vr.y,lb),   bfhi_(p.x), acc);
  acc = fmaf(rlf_(vr.x,lb+1), bflo_(p.y), acc);
  acc = fmaf(rlf_(vr.y,lb+1), bfhi_(p.y), acc);
  acc = fmaf(rlf_(vr.x,lb+2), bflo_(p.z), acc);
  acc = fmaf(rlf_(vr.y,lb+2), bfhi_(p.z), acc);
  acc = fmaf(rlf_(vr.x,lb+3), bflo_(p.w), acc);
  acc = fmaf(rlf_(vr.y,lb+3), bfhi_(p.w), acc);
  return acc;
}

// ===================== kPrep: weight pack (kConv) + input GEMM (kPre), merged ======
__global__ void __launch_bounds__(256)
kPrep(const float* __restrict__ W_hid, const float* __restrict__ W_iface,
      const float* __restrict__ x, const float* __restrict__ b_hid,
      float* __restrict__ ws)
{
  // --- pack + transpose recurrent-path weights (bf16) ---
  unsigned* Wip = (unsigned*)(ws + O_WIP);
  unsigned* Whp = (unsigned*)(ws + O_WHP);
  int g = blockIdx.x*256 + threadIdx.x;          // 65536 threads
  for (int i = g; i < 471*256; i += 65536) {
    int c = i >> 8, kp = i & 255;
    Wip[c*WIPS + kp] = bf16pack_(W_iface[(size_t)(2*kp)*IFACE_N + c],
                                 W_iface[(size_t)(2*kp+1)*IFACE_N + c]);
  }
  {
    int c = g >> 7, kp = g & 127;
    Whp[c*WHPS + kp] = bf16pack_(W_hid[(size_t)(512 + 2*kp)*512 + c],
                                 W_hid[(size_t)(513 + 2*kp)*512 + c]);
  }

  // --- hx = x @ W_hid[0:512] + b (kPre body; independent of the packing above) ---
  const int tid = threadIdx.x, blk = blockIdx.x;
  const int r0 = (blk >> 1) * 8, col = (blk & 1) * 256 + tid;
  __shared__ float xs[8][512];
  for (int i = tid; i < 8*512; i += 256) {
    int rr = i >> 9, k = i & 511;
    xs[rr][k] = x[(size_t)(r0+rr)*512 + k];
  }
  __syncthreads();
  float a0=0,a1=0,a2=0,a3=0,a4=0,a5=0,a6=0,a7=0;
  const float* Wp = W_hid + col;
#pragma unroll 4
  for (int k = 0; k < 512; k++) {
    float w = Wp[(size_t)k*512];
    a0 = fmaf(xs[0][k], w, a0); a1 = fmaf(xs[1][k], w, a1);
    a2 = fmaf(xs[2][k], w, a2); a3 = fmaf(xs[3][k], w, a3);
    a4 = fmaf(xs[4][k], w, a4); a5 = fmaf(xs[5][k], w, a5);
    a6 = fmaf(xs[6][k], w, a6); a7 = fmaf(xs[7][k], w, a7);
  }
  float bh = b_hid[col];
  float av[8] = {a0,a1,a2,a3,a4,a5,a6,a7};
#pragma unroll
  for (int i = 0; i < 8; i++)
    ws[O_HX + (size_t)(r0+i)*512 + col] = av[i] + bh;
}

// iface value x (<471) read directly from k-split psum (no combine phase)
#define IFC(x) (psum[(x)] + psum[512+(x)])

// ===================== kLoop: 16 independent per-batch blocks, all 64 steps =======
__global__ void __launch_bounds__(1024, 4)
kLoop(const unsigned* __restrict__ WipT, const unsigned* __restrict__ WhpT,
      float* __restrict__ hx, float* __restrict__ rvs, float* __restrict__ Lall)
{
  const int tid = threadIdx.x, b = blockIdx.x;
  const int wv = tid >> 6, lane = tid & 63;

  __shared__ float hl[512];
  __shared__ float psum[1024];
  __shared__ alignas(16) float ul[256];
  __shared__ alignas(16) float pOl[256];
  __shared__ float pNl[256];
  __shared__ alignas(16) float wwl[256];
  __shared__ alignas(16) float rwl[1024];
  __shared__ float wkn[64], rknl[256];
  __shared__ alignas(16) float evl[64], wvl[64];
  __shared__ float ssorted[256];
  __shared__ int   sidx[256];
  __shared__ float sal[256], siml[256], cwl[256];
  __shared__ float fwdl[1024], bwdl[1024], rcs[1024];
  __shared__ alignas(16) float bb[16][2][260];
  __shared__ float rvl[256];
  __shared__ float sSa;
  __shared__ alignas(16) float Ml[16384];    // M lives in LDS (block-private)

  float* Lg = Lall + (size_t)b*65536;

  // prologue: zero this block's L slice (replaces kInit), init state
  {
    float4 z4 = {0.f, 0.f, 0.f, 0.f};
    float4* Lz = (float4*)Lg;
    for (int i = tid; i < 16384; i += 1024) Lz[i] = z4;
  }
  if (tid < 512) hl[tid] = fmaxf(hx[(size_t)b*512 + tid], 0.f);   // h(0)
  rwl[tid] = 0.f;
  if (tid < 256){ ul[tid]=0.f; pOl[tid]=0.f; wwl[tid]=0.f; }
  for (int i = tid; i < 16384; i += 1024) Ml[i] = 1e-6f;
  __syncthreads();

  for (int t = 0; t < TS; t++) {
    // ---- P1: iface = h @ W_iface (bf16, distributed-h + readlane) ----
    {
      int col = tid & 511, kseg = tid >> 9;
      // one ds_read_b128 per lane distributes this wave's 256 h values
      float4 vh = *(const float4*)(hl + kseg*256 + (lane << 2));
      float a0 = 0.f, a1 = 0.f;
      if (col < IFACE_N) {
        const uint4* Wp = (const uint4*)(WipT + col*WIPS + kseg*128);
#pragma unroll
        for (int q4 = 0; q4 < 32; q4 += 2) {
          a0 = dot8rl_(Wp[q4],   vh, 2*q4,     a0);
          a1 = dot8rl_(Wp[q4+1], vh, 2*q4 + 2, a1);
        }
      }
      psum[tid] = a0 + a1;
    }
    __syncthreads();

    // ---- P2: usage update + key norms + gate vectors (read psum pairs) ----
    if (tid < 256) {
      float ret = 1.f;
#pragma unroll
      for (int r = 0; r < 4; r++) {
        float fg = sigmoidf_(IFC(OFF_FG + r));
        ret *= (1.f - fg * rwl[r*256 + tid]);
      }
      float uo = ul[tid], wo = wwl[tid];
      ul[tid] = (uo + wo - uo*wo) * ret;
    } else if (tid >= 448 && tid < 512) {              // wave 7: wk norm
      float kv = IFC(OFF_WK + lane);
      float ss = wsum_(kv*kv);
      wkn[lane] = kv / (sqrtf(ss) + EPS_);
    } else if (tid >= 512 && tid < 768) {              // waves 8..11: rk norms
      int r = wv - 8;
      float kv = IFC(OFF_RK + r*64 + lane);
      float ss = wsum_(kv*kv);
      rknl[r*64 + lane] = kv / (sqrtf(ss) + EPS_);
    } else if (tid >= 768 && tid < 832) {              // wave 12: erase vec
      evl[lane] = sigmoidf_(IFC(OFF_EV + lane));
    } else if (tid >= 832 && tid < 896) {              // wave 13: write vec
      wvl[lane] = IFC(OFF_WV + lane);
    }
    __syncthreads();

    // ---- P3: MERGED stable rank argsort + content-dot over OLD M ----
    {
      int n = tid >> 2, q = tid & 3;
      const float4* Mp = (const float4*)(Ml + n*64 + q*16);
      float4 m0 = Mp[0], m1 = Mp[1], m2 = Mp[2], m3 = Mp[3];
      float un = ul[n];
      const float4* sp4 = (const float4*)(ul + q*64);
      int cnt = 0;
#pragma unroll 4
      for (int m4 = 0; m4 < 16; m4++) {
        float4 um = sp4[m4];
        int gm = q*64 + m4*4;
        cnt += (um.x < un || (um.x == un && gm   < n)) ? 1 : 0;
        cnt += (um.y < un || (um.y == un && gm+1 < n)) ? 1 : 0;
        cnt += (um.z < un || (um.z == un && gm+2 < n)) ? 1 : 0;
        cnt += (um.w < un || (um.w == un && gm+3 < n)) ? 1 : 0;
      }
      cnt += __shfl_xor(cnt, 1, 64);
      cnt += __shfl_xor(cnt, 2, 64);
      const float* kp = wkn + q*16;
      float ss = m0.x*m0.x + m0.y*m0.y + m0.z*m0.z + m0.w*m0.w
               + m1.x*m1.x + m1.y*m1.y + m1.z*m1.z + m1.w*m1.w
               + m2.x*m2.x + m2.y*m2.y + m2.z*m2.z + m2.w*m2.w
               + m3.x*m3.x + m3.y*m3.y + m3.z*m3.z + m3.w*m3.w;
      float dt = m0.x*kp[0] + m0.y*kp[1] + m0.z*kp[2] + m0.w*kp[3]
               + m1.x*kp[4] + m1.y*kp[5] + m1.z*kp[6] + m1.w*kp[7]
               + m2.x*kp[8] + m2.y*kp[9] + m2.z*kp[10] + m2.w*kp[11]
               + m3.x*kp[12] + m3.y*kp[13] + m3.z*kp[14] + m3.w*kp[15];
      ss += __shfl_xor(ss,1,64); ss += __shfl_xor(ss,2,64);
      dt += __shfl_xor(dt,1,64); dt += __shfl_xor(dt,2,64);
      if (q == 0) {
        ssorted[cnt] = un; sidx[cnt] = n;
        float wb = oneplusf_(IFC(OFF_WB));
        siml[n] = wb * dt / (sqrtf(ss) + EPS_);
      }
    }
    __syncthreads();

    // ---- P4: cumprod alloc + Sa (wave 0) | write softmax (waves 4..7) ----
    if (wv == 0) {
      float carry = 1.f;
      float s_acc = 0.f;
#pragma unroll
      for (int c2 = 0; c2 < 4; c2++) {
        float v0 = ssorted[c2*64 + lane];
        float v = v0;
#pragma unroll
        for (int off = 1; off < 64; off <<= 1) {
          float uu = __shfl_up(v, off, 64);
          if (lane >= off) v *= uu;
        }
        float e = __shfl_up(v, 1, 64);
        if (lane == 0) e = 1.f;
        float av = (1.f - v0) * e * carry;
        sal[sidx[c2*64 + lane]] = av;
        s_acc += av;
        carry *= __shfl(v, 63, 64);
      }
      float S = wsum_(s_acc);
      if (lane == 0) sSa = S;
    } else if (wv >= 4 && wv < 8) {
      int s = tid - 256;                   // 0..255
      float v0 = siml[lane], v1 = siml[64+lane], v2 = siml[128+lane], v3 = siml[192+lane];
      float mx = wmax_(fmaxf(fmaxf(v0,v1), fmaxf(v2,v3)));
      float ssum = wsum_(expf(v0-mx)+expf(v1-mx)+expf(v2-mx)+expf(v3-mx));
      cwl[s] = expf(siml[s]-mx) / ssum;
    }
    __syncthreads();

    // ---- P5: ww + pN (wws analytic: sum(cw)=1, sum(a)=Sa) ----
    if (tid < 256) {
      float ag = sigmoidf_(IFC(OFF_AG));
      float wg = sigmoidf_(IFC(OFF_WG));
      float wwn = wg * (ag*sal[tid] + (1.f-ag)*cwl[tid]);
      wwl[tid] = wwn;
      float wws = wg * (ag*sSa + (1.f-ag));
      pNl[tid] = (1.f - wws)*pOl[tid] + wwn;
    }
    __syncthreads();

    // ---- P7: L update + fwd (4-value butterfly per row) + bwd (2-round bb
    //          staging, with P8 (M update + rc logits) overlapped on waves 8..15) ----
    {
      const int j0 = lane*4;
      const float4 wj  = *(const float4*)(wwl + j0);
      const float4 pj  = *(const float4*)(pOl + j0);
      const float4 rw0 = *(const float4*)(rwl + j0);
      const float4 rw1 = *(const float4*)(rwl + 256 + j0);
      const float4 rw2 = *(const float4*)(rwl + 512 + j0);
      const float4 rw3 = *(const float4*)(rwl + 768 + j0);
      // distributed wave-uniform values: lane l holds rw[head l>>4][row l&15],
      // and ww[row l&15]; accessed via readlane (VALU) instead of DS broadcasts.
      float vrw = rwl[(lane >> 4)*256 + wv*16 + (lane & 15)];
      float vww = wwl[wv*16 + (lane & 15)];
      float4 ba0 = {0,0,0,0}, ba1 = {0,0,0,0}, ba2 = {0,0,0,0}, ba3 = {0,0,0,0};
      float4* Lrow = (float4*)Lg;
#pragma unroll 4
      for (int ii = 0; ii < 16; ii++) {
        int i = wv*16 + ii;
        float wwi = rlf_(vww, ii);
        float4 lv = Lrow[i*64 + lane];
        float s = 1.f - wwi;
        float4 nv;
        nv.x = (s - wj.x)*lv.x + wwi*pj.x;
        nv.y = (s - wj.y)*lv.y + wwi*pj.y;
        nv.z = (s - wj.z)*lv.z + wwi*pj.z;
        nv.w = (s - wj.w)*lv.w + wwi*pj.w;
        if (j0   == i) nv.x = 0.f;
        if (j0+1 == i) nv.y = 0.f;
        if (j0+2 == i) nv.z = 0.f;
        if (j0+3 == i) nv.w = 0.f;
        Lrow[i*64 + lane] = nv;
        float f0 = nv.x*rw0.x + nv.y*rw0.y + nv.z*rw0.z + nv.w*rw0.w;
        float f1 = nv.x*rw1.x + nv.y*rw1.y + nv.z*rw1.z + nv.w*rw1.w;
        float f2 = nv.x*rw2.x + nv.y*rw2.y + nv.z*rw2.z + nv.w*rw2.w;
        float f3 = nv.x*rw3.x + nv.y*rw3.y + nv.z*rw3.z + nv.w*rw3.w;
        // 4-value wave reduction: transpose onto lane&3, then 4 xor levels.
        float u0 = (lane & 1) ? f1 : f0;
        float v0 = (lane & 1) ? f0 : f1;
        u0 += __shfl_xor(v0, 1, 64);
        float u1 = (lane & 1) ? f3 : f2;
        float v1 = (lane & 1) ? f2 : f3;
        u1 += __shfl_xor(v1, 1, 64);
        float u2 = (lane & 2) ? u1 : u0;
        float v2 = (lane & 2) ? u0 : u1;
        u2 += __shfl_xor(v2, 2, 64);
        u2 += __shfl_xor(u2, 4, 64);
        u2 += __shfl_xor(u2, 8, 64);
        u2 += __shfl_xor(u2, 16, 64);
        u2 += __shfl_xor(u2, 32, 64);
        if (lane < 4) fwdl[lane*256 + i] = u2;     // lane k holds sum of f_k
        float ri0 = rlf_(vrw, ii);
        float ri1 = rlf_(vrw, 16 + ii);
        float ri2 = rlf_(vrw, 32 + ii);
        float ri3 = rlf_(vrw, 48 + ii);
        ba0.x = fmaf(ri0, nv.x, ba0.x); ba0.y = fmaf(ri0, nv.y, ba0.y);
        ba0.z = fmaf(ri0, nv.z, ba0.z); ba0.w = fmaf(ri0, nv.w, ba0.w);
        ba1.x = fmaf(ri1, nv.x, ba1.x); ba1.y = fmaf(ri1, nv.y, ba1.y);
        ba1.z = fmaf(ri1, nv.z, ba1.z); ba1.w = fmaf(ri1, nv.w, ba1.w);
        ba2.x = fmaf(ri2, nv.x, ba2.x); ba2.y = fmaf(ri2, nv.y, ba2.y);
        ba2.z = fmaf(ri2, nv.z, ba2.z); ba2.w = fmaf(ri2, nv.w, ba2.w);
        ba3.x = fmaf(ri3, nv.x, ba3.x); ba3.y = fmaf(ri3, nv.y, ba3.y);
        ba3.z = fmaf(ri3, nv.z, ba3.z); ba3.w = fmaf(ri3, nv.w, ba3.w);
      }

      // save h(t) here: its store drains with the L stores at the next barrier
      if (tid < 512) hx[(size_t)(t*16 + b)*512 + tid] = hl[tid];

      // bwd staging: 2 rounds, 2 heads per round; P8 halves run on waves 8..15
#pragma unroll
      for (int rr = 0; rr < 2; rr++) {
        float4 vA = (rr == 0) ? ba0 : ba2;
        float4 vB = (rr == 0) ? ba1 : ba3;
        *(float4*)&bb[wv][0][j0] = vA;
        *(float4*)&bb[wv][1][j0] = vB;
        __syncthreads();
        if (tid < 512) {
          int r2 = tid >> 8, col = tid & 255;
          float s = 0.f;
#pragma unroll
          for (int w2 = 0; w2 < 16; w2++) s += bb[w2][r2][col];
          bwdl[(rr*2 + r2)*256 + col] = s;
          if (rr == 1 && tid < 256) pOl[tid] = pNl[tid];
        } else {
          // P8 half: M update + rc logits for n in [rr*128, rr*128+128)
          int s2 = tid - 512;                 // 0..511
          int n = rr*128 + (s2 >> 2), q = s2 & 3;
          float wwn = wwl[n];
          float4* Mp = (float4*)(Ml + n*64 + q*16);
          float ss = 0.f, d0 = 0.f, d1 = 0.f, d2 = 0.f, d3 = 0.f;
#pragma unroll
          for (int i = 0; i < 4; i++) {
            float4 mv = Mp[i];
            int w0 = q*16 + i*4;
            float4 ev = *(const float4*)(evl + w0);
            float4 wq = *(const float4*)(wvl + w0);
            float4 nv;
            nv.x = mv.x*(1.f - wwn*ev.x) + wwn*wq.x;
            nv.y = mv.y*(1.f - wwn*ev.y) + wwn*wq.y;
            nv.z = mv.z*(1.f - wwn*ev.z) + wwn*wq.z;
            nv.w = mv.w*(1.f - wwn*ev.w) + wwn*wq.w;
            Mp[i] = nv;
            ss += nv.x*nv.x + nv.y*nv.y + nv.z*nv.z + nv.w*nv.w;
            const float* k0 = rknl + w0;
            const float* k1 = rknl + 64 + w0;
            const float* k2 = rknl + 128 + w0;
            const float* k3 = rknl + 192 + w0;
            d0 += nv.x*k0[0] + nv.y*k0[1] + nv.z*k0[2] + nv.w*k0[3];
            d1 += nv.x*k1[0] + nv.y*k1[1] + nv.z*k1[2] + nv.w*k1[3];
            d2 += nv.x*k2[0] + nv.y*k2[1] + nv.z*k2[2] + nv.w*k2[3];
            d3 += nv.x*k3[0] + nv.y*k3[1] + nv.z*k3[2] + nv.w*k3[3];
          }
          // transpose d0..d3 onto lane&3 within the quad, full ss reduce
          float a  = (lane & 1) ? d1 : d0;
          float bq = (lane & 1) ? d0 : d1;
          a += __shfl_xor(bq, 1, 64);
          float c2 = (lane & 1) ? d3 : d2;
          float dq = (lane & 1) ? d2 : d3;
          c2 += __shfl_xor(dq, 1, 64);
          float e  = (lane & 2) ? c2 : a;
          float fq = (lane & 2) ? a : c2;
          e += __shfl_xor(fq, 2, 64);
          ss += __shfl_xor(ss,1,64); ss += __shfl_xor(ss,2,64);
          float inv = 1.f/(sqrtf(ss) + EPS_);
          rcs[q*256 + n] = oneplusf_(IFC(OFF_RB + q)) * e * inv;
        }
        __syncthreads();
      }
    }

    // ---- P9: rc softmax ----
    if (wv < 4) {
      float* rp = rcs + wv*256;
      float v0 = rp[lane], v1 = rp[64+lane], v2 = rp[128+lane], v3 = rp[192+lane];
      float mx = wmax_(fmaxf(fmaxf(v0,v1), fmaxf(v2,v3)));
      float e0 = expf(v0-mx), e1 = expf(v1-mx), e2 = expf(v2-mx), e3 = expf(v3-mx);
      float inv = 1.f / wsum_(e0+e1+e2+e3);
      rp[lane] = e0*inv; rp[64+lane] = e1*inv; rp[128+lane] = e2*inv; rp[192+lane] = e3*inv;
    }
    __syncthreads();

    // ---- P10: rw_new (rm weights from psum pairs) ----
    {
      int r = tid >> 8;
      float e0 = IFC(OFF_RM + r*3+0), e1 = IFC(OFF_RM + r*3+1), e2 = IFC(OFF_RM + r*3+2);
      float mx = fmaxf(e0, fmaxf(e1, e2));
      float x0 = expf(e0-mx), x1 = expf(e1-mx), x2 = expf(e2-mx);
      float inv = 1.f/(x0+x1+x2);
      rwl[tid] = (x0*bwdl[tid] + x1*rcs[tid] + x2*fwdl[tid]) * inv;
    }
    __syncthreads();

    // ---- P11: rv_new (M from LDS; rw distributed + readlane) ----
    {
      int w = tid & 63, r = (tid >> 6) & 3, c = tid >> 8;
      float vrp = rwl[r*256 + c*64 + lane];   // 1 ds_read; values uniform per wave
      const float* Mp = Ml + c*4096 + w;
      float a0 = 0.f, a1 = 0.f;
#pragma unroll
      for (int n = 0; n < 64; n += 2) {
        a0 = fmaf(Mp[(n  )*64], rlf_(vrp, n  ), a0);
        a1 = fmaf(Mp[(n+1)*64], rlf_(vrp, n+1), a1);
      }
      psum[c*256 + r*64 + w] = a0 + a1;
    }
    __syncthreads();
    if (tid < 256) {
      float v = psum[tid] + psum[256+tid] + psum[512+tid] + psum[768+tid];
      rvl[tid] = v;
      rvs[(size_t)(t*16 + b)*256 + tid] = v;    // save for deferred out GEMM
    }
    __syncthreads();

    // ---- P12: h(t+1) = relu(hx(t+1) + rv @ W_hid[512:768], distributed rv) ----
    if (t + 1 < TS) {
      int col = tid & 511, kseg = tid >> 9;
      float2 vr = *(const float2*)(rvl + kseg*128 + (lane << 1));
      const uint4* Wp = (const uint4*)(WhpT + col*WHPS + kseg*64);
      float a0 = 0.f, a1 = 0.f;
#pragma unroll
      for (int q4 = 0; q4 < 16; q4 += 2) {
        a0 = dot8rl2_(Wp[q4],   vr, 4*q4,     a0);
        a1 = dot8rl2_(Wp[q4+1], vr, 4*q4 + 4, a1);
      }
      psum[tid] = a0 + a1;
      __syncthreads();
      if (tid < 512)
        hl[tid] = fmaxf(hx[(size_t)((t+1)*16 + b)*512 + tid] + psum[tid] + psum[512+tid], 0.f);
      __syncthreads();
    }
  }
}

// ===================== kOut: out(t) = h(t)@W_out + rv(t)@W_memout (all t) =========
__global__ void __launch_bounds__(1024)
kOut(const float* __restrict__ W_out, const float* __restrict__ W_memout,
     const float* __restrict__ hsv, const float* __restrict__ rvs,
     float* __restrict__ out)
{
  const int tid = threadIdx.x, blk = blockIdx.x;
  const int rg = blk >> 2, cq = blk & 3;
  __shared__ float hs[16*512];
  __shared__ float rs[16*256];
  for (int i = tid; i < 16*512; i += 1024) hs[i] = hsv[(size_t)rg*16*512 + i];
  for (int i = tid; i < 16*256; i += 1024) rs[i] = rvs[(size_t)rg*16*256 + i];
  __syncthreads();
  int c  = cq*128 + (tid & 127);
  int ro = tid >> 7;                    // 0..7 -> rows 2*ro, 2*ro+1
  const float* h0 = hs + (2*ro)*512;
  const float* h1 = h0 + 512;
  const float* r0 = rs + (2*ro)*256;
  const float* r1 = r0 + 256;
  float a0 = 0.f, a1 = 0.f;
  const float* Wp = W_out + c;
#pragma unroll 8
  for (int k = 0; k < 512; k++) {
    float w = Wp[(size_t)k*512];
    a0 = fmaf(h0[k], w, a0);
    a1 = fmaf(h1[k], w, a1);
  }
  const float* Wm = W_memout + c;
#pragma unroll 8
  for (int k = 0; k < 256; k++) {
    float w = Wm[(size_t)k*512];
    a0 = fmaf(r0[k], w, a0);
    a1 = fmaf(r1[k], w, a1);
  }
  out[(size_t)(rg*16 + 2*ro)*512 + c]     = a0;
  out[(size_t)(rg*16 + 2*ro + 1)*512 + c] = a1;
}

extern "C" void kernel_launch(void* const* d_in, const int* in_sizes, int n_in,
                              void* d_out, int out_size, void* d_ws, size_t ws_size,
                              hipStream_t stream) {
  (void)in_sizes; (void)n_in; (void)out_size; (void)ws_size;
  const float* x        = (const float*)d_in[0];
  const float* W_hid    = (const float*)d_in[1];
  const float* b_hid    = (const float*)d_in[2];
  const float* W_iface  = (const float*)d_in[3];
  const float* W_out    = (const float*)d_in[4];
  const float* W_memout = (const float*)d_in[5];
  float* outp = (float*)d_out;
  float* ws   = (float*)d_ws;

  hipLaunchKernelGGL(kPrep, dim3(256), dim3(256), 0, stream,
                     W_hid, W_iface, x, b_hid, ws);

  const unsigned* WipT = (const unsigned*)(ws + O_WIP);
  const unsigned* WhpT = (const unsigned*)(ws + O_WHP);
  float* hx   = ws + O_HX;
  float* rvs  = ws + O_RS;
  float* Lall = ws + O_L;

  hipLaunchKernelGGL(kLoop, dim3(16), dim3(1024), 0, stream,
                     WipT, WhpT, hx, rvs, Lall);
  hipLaunchKernelGGL(kOut, dim3(256), dim3(1024), 0, stream,
                     W_out, W_memout, hx, rvs, outp);
}